// Round 1
// baseline (26.588 us; speedup 1.0000x reference)
//
#include <hip/hip_runtime.h>

// ST-BIF neuron, multi-step. Module constants (from reference):
//   V_TH = 0.5 (q_threshold), LEVEL = 16, sym = False -> T_MAX = 15, T_MIN = 0
//   PREFIRE = 0.0 -> the "pre" subtraction term is exactly 0 every step.
// Per-element recurrence over T time steps; elements independent across BF.

constexpr float V_TH   = 0.5f;
constexpr float T_MAXF = 15.0f;   // level - 1
constexpr int   T_STEPS = 8;      // from setup_inputs: x is [T*B,...] with T=8

__global__ __launch_bounds__(256) void st_bif_kernel(
    const float* __restrict__ x,   // [T, BF] flattened
    float* __restrict__ out,       // [T, BF]
    int BF)                        // features per time step (multiple of 4)
{
    const int i = (blockIdx.x * blockDim.x + threadIdx.x) * 4;
    if (i >= BF) return;

    // v initialized to 0.5*v_th + prefire*v_th = 0.25 ; Tc = 0
    float v[4]  = {0.25f, 0.25f, 0.25f, 0.25f};
    float Tc[4] = {0.f, 0.f, 0.f, 0.f};

    #pragma unroll
    for (int t = 0; t < T_STEPS; ++t) {
        const size_t base = (size_t)t * (size_t)BF + (size_t)i;
        const float4 xt = *reinterpret_cast<const float4*>(x + base);
        const float xs[4] = {xt.x, xt.y, xt.z, xt.w};
        float os[4];
        #pragma unroll
        for (int j = 0; j < 4; ++j) {
            v[j] += xs[j];
            const bool pos = (v[j] >= V_TH) && (Tc[j] < T_MAXF);
            const bool neg = (v[j] < 0.0f)  && (Tc[j] > 0.0f);
            const float spike = pos ? 1.0f : (neg ? -1.0f : 0.0f);
            v[j]  -= V_TH * spike;   // pre term is 0 (PREFIRE == 0)
            Tc[j] += spike;
            os[j]  = spike * V_TH;   // output = spike * q_threshold
        }
        float4 o;
        o.x = os[0]; o.y = os[1]; o.z = os[2]; o.w = os[3];
        *reinterpret_cast<float4*>(out + base) = o;
    }
}

extern "C" void kernel_launch(void* const* d_in, const int* in_sizes, int n_in,
                              void* d_out, int out_size, void* d_ws, size_t ws_size,
                              hipStream_t stream) {
    const float* x = (const float*)d_in[0];
    float* out = (float*)d_out;

    const int total = in_sizes[0];           // 16,777,216
    const int BF = total / T_STEPS;          // 2,097,152 (features per step)

    const int threads = 256;
    const int lanes = BF / 4;                // one thread per 4 features
    const int blocks = (lanes + threads - 1) / threads;  // 2048

    st_bif_kernel<<<blocks, threads, 0, stream>>>(x, out, BF);
}